// Round 4
// baseline (196395.447 us; speedup 1.0000x reference)
//
#include <hip/hip_runtime.h>

// Problem sizes (fixed).
#define T_STEPS 65536
#define SCHUNK 128              // steps per pipeline chunk
#define NCHUNK 512              // T_STEPS / SCHUNK
#define RING 8                  // h1 ring slots (power of 2)

// ws float layout (peak 41,943,040 floats = 167.77 MB, same as R0):
//  A1/A2   @ 0          (16,777,216)  A2 overwrites A1 chunk-by-chunk (dead)
//  C1X/C2X @ 16777216   ( 8,388,608)  same trick
//  H1 ring @ 25165824   (   131,072)  8 slots x 128 steps x 128
//  flags   @ 25296896   (     2,560 ints)
//  X       @ 33554432   ( 8,388,608)  phase-1 only (dead before YS written)
//  YS      @ 33554432   ( 8,388,608)  phase-2 output
//  PIb     @ 0, Vb @ 8388608          phase-3 (A2 dead)

typedef float f2 __attribute__((ext_vector_type(2)));
typedef float f4 __attribute__((ext_vector_type(4)));

__device__ __forceinline__ float sigmoid_f(float x) {
  float e = __expf(-x);
  return __builtin_amdgcn_rcpf(1.0f + e);
}
__device__ __forceinline__ float tanh_f(float x) {
  float e = __expf(-2.0f * x);
  return (1.0f - e) * __builtin_amdgcn_rcpf(1.0f + e);
}

// LDS-only barrier (no vmcnt drain; global prefetch stays in flight).
__device__ __forceinline__ void bar_lds() {
  asm volatile("s_waitcnt lgkmcnt(0)\n\ts_barrier" ::: "memory");
}

__device__ __forceinline__ float rdlane(float v, int lane) {
  return __int_as_float(__builtin_amdgcn_readlane(__float_as_int(v), lane));
}

// Device-scope flag ops (cross-XCD producer/consumer).
__device__ __forceinline__ void spin_flag(int* p) {
  while (__hip_atomic_load(p, __ATOMIC_ACQUIRE, __HIP_MEMORY_SCOPE_AGENT) == 0)
    __builtin_amdgcn_s_sleep(8);
}
__device__ __forceinline__ void set_flag(int* p) {
  __hip_atomic_store(p, 1, __ATOMIC_RELEASE, __HIP_MEMORY_SCOPE_AGENT);
}

// ---------------------------------------------------------------------------
// Generic K=128 GEMM: OUT[T][N] = act(IN[T][128] @ W[128][N] + bias[N])
// ---------------------------------------------------------------------------
__global__ __launch_bounds__(256)
void gemm_k128(const float* __restrict__ IN, const float* __restrict__ W,
               const float* __restrict__ bias, float* __restrict__ OUT,
               int N, int relu) {
  __shared__ __align__(16) float in_t[32][132];
  const int tid = threadIdx.x;
  const int ct = tid & 63;
  const int rt = tid >> 6;
  const int R0 = blockIdx.x * 32;

  const f4* src = (const f4*)(IN + (size_t)R0 * 128);
#pragma unroll
  for (int q = 0; q < 4; ++q) {
    int f4i = tid + 256 * q;
    int r = f4i >> 5, c4 = f4i & 31;
    f4 v = src[f4i];
    *(f4*)&in_t[r][c4 * 4] = v;
  }
  __syncthreads();

  f2 acc[8][4];
#pragma unroll
  for (int r = 0; r < 8; ++r)
#pragma unroll
    for (int m = 0; m < 4; ++m) acc[r][m] = (f2)0.0f;

  for (int kp = 0; kp < 64; ++kp) {
    f2 iv[8];
#pragma unroll
    for (int r = 0; r < 8; ++r)
      iv[r] = *(const f2*)&in_t[rt * 8 + r][2 * kp];
    f2 wv[4];
#pragma unroll
    for (int m = 0; m < 4; ++m) {
      int c = ct + 64 * m;
      if (c < N) {
        wv[m].x = W[(2 * kp) * N + c];
        wv[m].y = W[(2 * kp + 1) * N + c];
      } else {
        wv[m] = (f2)0.0f;
      }
    }
#pragma unroll
    for (int r = 0; r < 8; ++r)
#pragma unroll
      for (int m = 0; m < 4; ++m)
        acc[r][m] = __builtin_elementwise_fma(iv[r], wv[m], acc[r][m]);
  }

#pragma unroll
  for (int m = 0; m < 4; ++m) {
    int c = ct + 64 * m;
    if (c < N) {
      float b = bias[c];
#pragma unroll
      for (int r = 0; r < 8; ++r) {
        float v = acc[r][m].x + acc[r][m].y + b;
        if (relu) v = fmaxf(v, 0.0f);
        OUT[(size_t)(R0 + rt * 8 + r) * N + c] = v;
      }
    }
  }
}

// ---------------------------------------------------------------------------
// GRU step (Plan X, identical math to R3): register-held state, readlane
// broadcast, stride-5 partials in LDS, 2 LDS-only barriers.
// ---------------------------------------------------------------------------
#define GRU_STEP(LT, AR, AU, CXV)                                             \
  do {                                                                        \
    f2 ga0 = (f2)0.0f, ga1 = (f2)0.0f, ga2 = (f2)0.0f, ga3 = (f2)0.0f;        \
    _Pragma("unroll")                                                         \
    for (int qq = 0; qq < 16; ++qq) {                                         \
      f2 hp;                                                                  \
      hp.x = rdlane(hself, 2 * qq);                                           \
      hp.y = rdlane(hself, 2 * qq + 1);                                       \
      ga0 = __builtin_elementwise_fma(hp, wgt[qq][0], ga0);                   \
      ga1 = __builtin_elementwise_fma(hp, wgt[qq][1], ga1);                   \
      ga2 = __builtin_elementwise_fma(hp, wgt[qq][2], ga2);                   \
      ga3 = __builtin_elementwise_fma(hp, wgt[qq][3], ga3);                   \
    }                                                                         \
    pg[(l + 0) * 5 + w] = ga0.x + ga0.y;                                      \
    pg[(l + 64) * 5 + w] = ga1.x + ga1.y;                                     \
    pg[(l + 128) * 5 + w] = ga2.x + ga2.y;                                    \
    pg[(l + 192) * 5 + w] = ga3.x + ga3.y;                                    \
    bar_lds();                                                                \
    float rpre = ((pg[o_r * 5 + 0] + pg[o_r * 5 + 1]) +                       \
                  (pg[o_r * 5 + 2] + pg[o_r * 5 + 3])) + (AR);                \
    float upre = ((pg[o_u * 5 + 0] + pg[o_u * 5 + 1]) +                       \
                  (pg[o_u * 5 + 2] + pg[o_u * 5 + 3])) + (AU);                \
    float rg = sigmoid_f(rpre);                                               \
    float ugv = sigmoid_f(upre);                                              \
    float rhv = rg * hself;                                                   \
    f2 ca0 = (f2)0.0f, ca1 = (f2)0.0f;                                        \
    _Pragma("unroll")                                                         \
    for (int qq = 0; qq < 16; ++qq) {                                         \
      f2 rp;                                                                  \
      rp.x = rdlane(rhv, 2 * qq);                                             \
      rp.y = rdlane(rhv, 2 * qq + 1);                                         \
      ca0 = __builtin_elementwise_fma(rp, wct[qq][0], ca0);                   \
      ca1 = __builtin_elementwise_fma(rp, wct[qq][1], ca1);                   \
    }                                                                         \
    pc[(l + 0) * 5 + w] = ca0.x + ca0.y;                                      \
    pc[(l + 64) * 5 + w] = ca1.x + ca1.y;                                     \
    bar_lds();                                                                \
    float cpre = ((pc[o_r * 5 + 0] + pc[o_r * 5 + 1]) +                       \
                  (pc[o_r * 5 + 2] + pc[o_r * 5 + 3])) + (CXV);               \
    float cv = tanh_f(cpre);                                                  \
    hself = ugv * hself + (1.0f - ugv) * cv;                                  \
    if (half == 0) hc[(LT) * 128 + o_r] = hself;                              \
    bar_lds();                                                                \
  } while (0)

// ---------------------------------------------------------------------------
// Scan role (B0: producer -> h ring; B3: consumer of A2/C2X -> YS).
// ---------------------------------------------------------------------------
__device__ void scan_role(const float* __restrict__ A, const float* __restrict__ CX,
                          const float* __restrict__ Wgh, const float* __restrict__ Wch,
                          float* __restrict__ hout, int hout_is_ring,
                          float* __restrict__ hfinal,
                          int* relf, int* acka, int* ackb, int* wfa, int* wfb) {
  __shared__ float pg[256 * 5];
  __shared__ float pc[128 * 5];
  const int tid = threadIdx.x;
  const int w = tid >> 6;
  const int l = tid & 63;
  const int j = l & 31;
  const int half = l >> 5;
  const int o_r = 32 * w + j;
  const int o_u = o_r + 128;

  f2 wgt[16][4];
  f2 wct[16][2];
#pragma unroll
  for (int q = 0; q < 16; ++q) {
#pragma unroll
    for (int m = 0; m < 4; ++m) {
      wgt[q][m].x = Wgh[(32 * w + 2 * q) * 256 + l + 64 * m];
      wgt[q][m].y = Wgh[(32 * w + 2 * q + 1) * 256 + l + 64 * m];
    }
#pragma unroll
    for (int n = 0; n < 2; ++n) {
      wct[q][n].x = Wch[(32 * w + 2 * q) * 128 + l + 64 * n];
      wct[q][n].y = Wch[(32 * w + 2 * q + 1) * 128 + l + 64 * n];
    }
  }

  float hself = 0.0f;

  for (int c = 0; c < NCHUNK; ++c) {
    if (wfa) { spin_flag(&wfa[c]); spin_flag(&wfb[c]); }           // consumer gate
    if (relf && c >= RING) {                                       // ring-slot free?
      spin_flag(&acka[c - RING]);
      spin_flag(&ackb[c - RING]);
    }
    const float* Ac = A + (size_t)c * SCHUNK * 256;
    const float* Cc = CX + (size_t)c * SCHUNK * 128;
    float* hc = hout_is_ring ? hout + (size_t)(c & (RING - 1)) * SCHUNK * 128
                             : hout + (size_t)c * SCHUNK * 128;

    float arc[4], auc[4], cxc[4], arn[4], aun[4], cxn[4];
#pragma unroll
    for (int q = 0; q < 4; ++q) {
      arc[q] = Ac[q * 256 + o_r];
      auc[q] = Ac[q * 256 + o_u];
      cxc[q] = Cc[q * 128 + o_r];
    }
    for (int t0 = 0; t0 < SCHUNK; t0 += 4) {
      const int nb = (t0 + 4 < SCHUNK) ? t0 + 4 : 0;  // clamp inside chunk
#pragma unroll
      for (int q = 0; q < 4; ++q) {
        arn[q] = Ac[(nb + q) * 256 + o_r];
        aun[q] = Ac[(nb + q) * 256 + o_u];
        cxn[q] = Cc[(nb + q) * 128 + o_r];
      }
#pragma unroll
      for (int q = 0; q < 4; ++q) {
        GRU_STEP(t0 + q, arc[q], auc[q], cxc[q]);
      }
#pragma unroll
      for (int q = 0; q < 4; ++q) { arc[q] = arn[q]; auc[q] = aun[q]; cxc[q] = cxn[q]; }
    }
    if (relf) {
      __syncthreads();                 // drains ALL waves' stores (vmcnt 0)
      if (tid == 0) set_flag(&relf[c]);
    }
  }
  if (half == 0) hfinal[o_r] = hself;
}

// ---------------------------------------------------------------------------
// Relay GEMV role: OUT chunk = h1_chunk @ W_x + bias, chunk-wise behind B0.
// N=256 (gates) or N=128 (cand). One col per thread (N=128: rows split).
// ---------------------------------------------------------------------------
__device__ void gemv_role(const float* __restrict__ ring, const float* __restrict__ W,
                          const float* __restrict__ bias, float* __restrict__ OUT,
                          int N, int* inflag, int* ack, int* outflag) {
  const int tid = threadIdx.x;
  const int col = (N == 256) ? tid : (tid & 127);
  const int g0 = (N == 256) ? 0 : (tid >> 7) * 8;
  const int ng = (N == 256) ? 16 : 8;

  f2 wcol[64];
#pragma unroll
  for (int kq = 0; kq < 64; ++kq) {
    wcol[kq].x = W[(2 * kq) * N + col];
    wcol[kq].y = W[(2 * kq + 1) * N + col];
  }
  const float bcol = bias[col];

  for (int c = 0; c < NCHUNK; ++c) {
    spin_flag(&inflag[c]);
    const f4* rv = (const f4*)(ring + (size_t)(c & (RING - 1)) * SCHUNK * 128);
    const size_t r0 = (size_t)c * SCHUNK;
    for (int g = g0; g < g0 + ng; ++g) {
      f2 acc[8];
#pragma unroll
      for (int r = 0; r < 8; ++r) acc[r] = (f2)0.0f;
#pragma unroll 2
      for (int kq2 = 0; kq2 < 32; ++kq2) {
#pragma unroll
        for (int r = 0; r < 8; ++r) {
          f4 h4 = rv[(g * 8 + r) * 32 + kq2];   // wave-uniform broadcast load
          acc[r] = __builtin_elementwise_fma(h4.xy, wcol[2 * kq2], acc[r]);
          acc[r] = __builtin_elementwise_fma(h4.zw, wcol[2 * kq2 + 1], acc[r]);
        }
      }
#pragma unroll
      for (int r = 0; r < 8; ++r)
        OUT[(r0 + g * 8 + r) * N + col] = acc[r].x + acc[r].y + bcol;
    }
    __syncthreads();                   // drain all waves' loads+stores
    if (tid == 0) { set_flag(&outflag[c]); set_flag(&ack[c]); }
  }
}

// ---------------------------------------------------------------------------
// Pipeline kernel: 4 blocks = {scan1, gemvA2, gemvC2X, scan2}.
// ---------------------------------------------------------------------------
__global__ __launch_bounds__(256, 1)
void pipeline(const float* __restrict__ A1, const float* __restrict__ C1X,
              const float* __restrict__ Wg1, const float* __restrict__ Wc1,
              const float* __restrict__ Wg2, const float* __restrict__ bg2,
              const float* __restrict__ Wc2, const float* __restrict__ bc2,
              float* ring, float* A2, float* C2X, float* YS,
              float* h1f, float* h2f, int* flags) {
  int* flag1 = flags;          // h1 chunk ready
  int* acka  = flags + 512;    // gemvA2 consumed ring chunk
  int* ackb  = flags + 1024;   // gemvC2X consumed ring chunk
  int* f2a   = flags + 1536;   // A2 chunk ready
  int* f2b   = flags + 2048;   // C2X chunk ready
  const int role = blockIdx.x;
  if (role == 0)
    scan_role(A1, C1X, Wg1 + 128 * 256, Wc1 + 128 * 128, ring, 1, h1f,
              flag1, acka, ackb, nullptr, nullptr);
  else if (role == 1)
    gemv_role(ring, Wg2, bg2, A2, 256, flag1, acka, f2a);
  else if (role == 2)
    gemv_role(ring, Wc2, bc2, C2X, 128, flag1, ackb, f2b);
  else
    scan_role(A2, C2X, Wg2 + 128 * 256, Wc2 + 128 * 128, YS, 0, h2f,
              nullptr, nullptr, nullptr, f2a, f2b);
}

// ---------------------------------------------------------------------------
// Final projections: logits = PI @ Wp + bp, value = V @ Wv + bv.
// ---------------------------------------------------------------------------
__global__ __launch_bounds__(256)
void proj_heads(const float* __restrict__ PI, const float* __restrict__ V,
                const float* __restrict__ Wp, const float* __restrict__ bp,
                const float* __restrict__ Wv, const float* __restrict__ bv,
                float* __restrict__ logits, float* __restrict__ value) {
  __shared__ float pi_t[128][101];
  __shared__ float v_t[128][101];
  __shared__ float wp_s[100][18];
  __shared__ float wv_s[100];
  __shared__ float bp_s[18];
  __shared__ float bv_s;
  const int tid = threadIdx.x;
  const int R0 = blockIdx.x * 128;

  for (int idx = tid; idx < 12800; idx += 256) {
    int r = idx / 100, c = idx - r * 100;
    pi_t[r][c] = PI[(size_t)R0 * 100 + idx];
    v_t[r][c] = V[(size_t)R0 * 100 + idx];
  }
  for (int idx = tid; idx < 1800; idx += 256) ((float*)wp_s)[idx] = Wp[idx];
  if (tid < 100) wv_s[tid] = Wv[tid];
  if (tid < 18) bp_s[tid] = bp[tid];
  if (tid == 0) bv_s = bv[0];
  __syncthreads();

  const int r = tid >> 1, h = tid & 1;
  float acc[9];
#pragma unroll
  for (int m = 0; m < 9; ++m) acc[m] = bp_s[h * 9 + m];
  float vacc = bv_s;
#pragma unroll 4
  for (int c = 0; c < 100; ++c) {
    float p = pi_t[r][c];
#pragma unroll
    for (int m = 0; m < 9; ++m) acc[m] = fmaf(p, wp_s[c][h * 9 + m], acc[m]);
    if (h) vacc = fmaf(v_t[r][c], wv_s[c], vacc);
  }
  size_t t = (size_t)R0 + r;
#pragma unroll
  for (int m = 0; m < 9; ++m) logits[t * 18 + h * 9 + m] = acc[m];
  if (h) value[t] = vacc;
}

// ---------------------------------------------------------------------------
extern "C" void kernel_launch(void* const* d_in, const int* in_sizes, int n_in,
                              void* d_out, int out_size, void* d_ws, size_t ws_size,
                              hipStream_t stream) {
  const float* obs = (const float*)d_in[0];
  const float* W1  = (const float*)d_in[1];
  const float* b1  = (const float*)d_in[2];
  const float* Wg1 = (const float*)d_in[3];
  const float* bg1 = (const float*)d_in[4];
  const float* Wc1 = (const float*)d_in[5];
  const float* bc1 = (const float*)d_in[6];
  const float* Wg2 = (const float*)d_in[7];
  const float* bg2 = (const float*)d_in[8];
  const float* Wc2 = (const float*)d_in[9];
  const float* bc2 = (const float*)d_in[10];
  const float* W2  = (const float*)d_in[11];
  const float* b2  = (const float*)d_in[12];
  const float* W3  = (const float*)d_in[13];
  const float* b3  = (const float*)d_in[14];
  const float* Wp  = (const float*)d_in[15];
  const float* bp  = (const float*)d_in[16];
  const float* Wv  = (const float*)d_in[17];
  const float* bv  = (const float*)d_in[18];

  float* out = (float*)d_out;
  float* ws  = (float*)d_ws;
  const int T = T_STEPS;

  float* A1   = ws + 0;           // also A2 (overwritten chunk-wise)
  float* C1X  = ws + 16777216;    // also C2X
  float* ring = ws + 25165824;    // h1 ring (8 x 128 x 128)
  int*   flags = (int*)(ws + 25296896);   // 2560 ints
  float* X    = ws + 33554432;    // phase-1 scratch (dead before YS)
  float* YS   = ws + 33554432;
  float* PIb  = ws + 0;           // phase-3 (A2 dead)
  float* Vb   = ws + 8388608;

  float* logits = out;
  float* value  = out + (size_t)T * 18;
  float* h1f    = out + (size_t)T * 18 + T;
  float* h2f    = h1f + 128;

  dim3 b256(256);
  // Reset handoff flags (graph-captured; runs every replay before pipeline).
  hipMemsetAsync(flags, 0, 2560 * sizeof(int), stream);
  // Parallel pre-pass: X = relu(obs@W1+b1); x-parts of GRU1 preactivations.
  gemm_k128<<<T / 32, b256, 0, stream>>>(obs, W1, b1, X, 128, 1);
  gemm_k128<<<T / 32, b256, 0, stream>>>(X, Wg1, bg1, A1, 256, 0);
  gemm_k128<<<T / 32, b256, 0, stream>>>(X, Wc1, bc1, C1X, 128, 0);
  // Pipelined phase: scan1 -> relay GEMVs -> scan2, concurrent across CUs.
  pipeline<<<4, b256, 0, stream>>>(A1, C1X, Wg1, Wc1, Wg2, bg2, Wc2, bc2,
                                   ring, A1 /*A2*/, C1X /*C2X*/, YS,
                                   h1f, h2f, flags);
  // Parallel heads.
  gemm_k128<<<T / 32, b256, 0, stream>>>(YS, W2, b2, PIb, 100, 1);
  gemm_k128<<<T / 32, b256, 0, stream>>>(YS, W3, b3, Vb, 100, 1);
  proj_heads<<<T / 128, b256, 0, stream>>>(PIb, Vb, Wp, bp, Wv, bv, logits, value);
}

// Round 5
// 53061.023 us; speedup vs baseline: 3.7013x; 3.7013x over previous
//
#include <hip/hip_runtime.h>

// Problem sizes (fixed).
#define T_STEPS 65536
#define SCHUNK 128              // steps per pipeline chunk
#define NCHUNK 512              // T_STEPS / SCHUNK
#define RING 8                  // h1 ring slots (power of 2)

// ws float layout (peak 41,943,040 floats = 167.77 MB):
//  A1/A2   @ 0          (16,777,216)  A2 overwrites A1 chunk-by-chunk (dead)
//  C1X/C2X @ 16777216   ( 8,388,608)  same trick
//  H1 ring @ 25165824   (   131,072)  8 slots x 128 steps x 128
//  flags   @ 25296896   (     2,560 ints)
//  X       @ 33554432   ( 8,388,608)  dead once A1/C1X gemms finish
//  YS      @ 33554432   ( 8,388,608)  scan2 output (over X)
//  PIb     @ 0, Vb @ 8388608          phase-3 (A2 dead)

typedef float f2 __attribute__((ext_vector_type(2)));
typedef float f4 __attribute__((ext_vector_type(4)));

__device__ __forceinline__ float sigmoid_f(float x) {
  float e = __expf(-x);
  return __builtin_amdgcn_rcpf(1.0f + e);
}
__device__ __forceinline__ float tanh_f(float x) {
  float e = __expf(-2.0f * x);
  return (1.0f - e) * __builtin_amdgcn_rcpf(1.0f + e);
}

// LDS-only barrier (no vmcnt drain; global prefetch stays in flight).
__device__ __forceinline__ void bar_lds() {
  asm volatile("s_waitcnt lgkmcnt(0)\n\ts_barrier" ::: "memory");
}

__device__ __forceinline__ float rdlane(float v, int lane) {
  return __int_as_float(__builtin_amdgcn_readlane(__float_as_int(v), lane));
}

// Relaxed spin: polls bypass-cached but do NOT invalidate L2 per poll.
__device__ __forceinline__ void spin_rlx(int* p) {
  while (__hip_atomic_load(p, __ATOMIC_RELAXED, __HIP_MEMORY_SCOPE_AGENT) == 0)
    __builtin_amdgcn_s_sleep(8);
}
// Spin + ONE acquire (single L1/L2 invalidate per chunk, not per poll).
__device__ __forceinline__ void spin_acq(int* p) {
  spin_rlx(p);
  (void)__hip_atomic_load(p, __ATOMIC_ACQUIRE, __HIP_MEMORY_SCOPE_AGENT);
}
__device__ __forceinline__ void set_flag_rel(int* p) {
  __hip_atomic_store(p, 1, __ATOMIC_RELEASE, __HIP_MEMORY_SCOPE_AGENT);
}
__device__ __forceinline__ void set_flag_rlx(int* p) {
  __hip_atomic_store(p, 1, __ATOMIC_RELAXED, __HIP_MEMORY_SCOPE_AGENT);
}

// ---------------------------------------------------------------------------
// Generic K=128 GEMM: OUT[T][N] = act(IN[T][128] @ W[128][N] + bias[N])
// ---------------------------------------------------------------------------
__global__ __launch_bounds__(256)
void gemm_k128(const float* __restrict__ IN, const float* __restrict__ W,
               const float* __restrict__ bias, float* __restrict__ OUT,
               int N, int relu) {
  __shared__ __align__(16) float in_t[32][132];
  const int tid = threadIdx.x;
  const int ct = tid & 63;
  const int rt = tid >> 6;
  const int R0 = blockIdx.x * 32;

  const f4* src = (const f4*)(IN + (size_t)R0 * 128);
#pragma unroll
  for (int q = 0; q < 4; ++q) {
    int f4i = tid + 256 * q;
    int r = f4i >> 5, c4 = f4i & 31;
    f4 v = src[f4i];
    *(f4*)&in_t[r][c4 * 4] = v;
  }
  __syncthreads();

  f2 acc[8][4];
#pragma unroll
  for (int r = 0; r < 8; ++r)
#pragma unroll
    for (int m = 0; m < 4; ++m) acc[r][m] = (f2)0.0f;

  for (int kp = 0; kp < 64; ++kp) {
    f2 iv[8];
#pragma unroll
    for (int r = 0; r < 8; ++r)
      iv[r] = *(const f2*)&in_t[rt * 8 + r][2 * kp];
    f2 wv[4];
#pragma unroll
    for (int m = 0; m < 4; ++m) {
      int c = ct + 64 * m;
      if (c < N) {
        wv[m].x = W[(2 * kp) * N + c];
        wv[m].y = W[(2 * kp + 1) * N + c];
      } else {
        wv[m] = (f2)0.0f;
      }
    }
#pragma unroll
    for (int r = 0; r < 8; ++r)
#pragma unroll
      for (int m = 0; m < 4; ++m)
        acc[r][m] = __builtin_elementwise_fma(iv[r], wv[m], acc[r][m]);
  }

#pragma unroll
  for (int m = 0; m < 4; ++m) {
    int c = ct + 64 * m;
    if (c < N) {
      float b = bias[c];
#pragma unroll
      for (int r = 0; r < 8; ++r) {
        float v = acc[r][m].x + acc[r][m].y + b;
        if (relu) v = fmaxf(v, 0.0f);
        OUT[(size_t)(R0 + rt * 8 + r) * N + c] = v;
      }
    }
  }
}

// ---------------------------------------------------------------------------
// GRU step (identical math to R3): register-held state, readlane broadcast,
// stride-5 partials in LDS, exactly 2 LDS-only barriers.
// ---------------------------------------------------------------------------
#define GRU_STEP(LT, AR, AU, CXV)                                             \
  do {                                                                        \
    f2 ga0 = (f2)0.0f, ga1 = (f2)0.0f, ga2 = (f2)0.0f, ga3 = (f2)0.0f;        \
    _Pragma("unroll")                                                         \
    for (int qq = 0; qq < 16; ++qq) {                                         \
      f2 hp;                                                                  \
      hp.x = rdlane(hself, 2 * qq);                                           \
      hp.y = rdlane(hself, 2 * qq + 1);                                       \
      ga0 = __builtin_elementwise_fma(hp, wgt[qq][0], ga0);                   \
      ga1 = __builtin_elementwise_fma(hp, wgt[qq][1], ga1);                   \
      ga2 = __builtin_elementwise_fma(hp, wgt[qq][2], ga2);                   \
      ga3 = __builtin_elementwise_fma(hp, wgt[qq][3], ga3);                   \
    }                                                                         \
    pg[(l + 0) * 5 + w] = ga0.x + ga0.y;                                      \
    pg[(l + 64) * 5 + w] = ga1.x + ga1.y;                                     \
    pg[(l + 128) * 5 + w] = ga2.x + ga2.y;                                    \
    pg[(l + 192) * 5 + w] = ga3.x + ga3.y;                                    \
    bar_lds();                                                                \
    float rpre = ((pg[o_r * 5 + 0] + pg[o_r * 5 + 1]) +                       \
                  (pg[o_r * 5 + 2] + pg[o_r * 5 + 3])) + (AR);                \
    float upre = ((pg[o_u * 5 + 0] + pg[o_u * 5 + 1]) +                       \
                  (pg[o_u * 5 + 2] + pg[o_u * 5 + 3])) + (AU);                \
    float rg = sigmoid_f(rpre);                                               \
    float ugv = sigmoid_f(upre);                                              \
    float rhv = rg * hself;                                                   \
    f2 ca0 = (f2)0.0f, ca1 = (f2)0.0f;                                        \
    _Pragma("unroll")                                                         \
    for (int qq = 0; qq < 16; ++qq) {                                         \
      f2 rp;                                                                  \
      rp.x = rdlane(rhv, 2 * qq);                                             \
      rp.y = rdlane(rhv, 2 * qq + 1);                                         \
      ca0 = __builtin_elementwise_fma(rp, wct[qq][0], ca0);                   \
      ca1 = __builtin_elementwise_fma(rp, wct[qq][1], ca1);                   \
    }                                                                         \
    pc[(l + 0) * 5 + w] = ca0.x + ca0.y;                                      \
    pc[(l + 64) * 5 + w] = ca1.x + ca1.y;                                     \
    bar_lds();                                                                \
    float cpre = ((pc[o_r * 5 + 0] + pc[o_r * 5 + 1]) +                       \
                  (pc[o_r * 5 + 2] + pc[o_r * 5 + 3])) + (CXV);               \
    float cv = tanh_f(cpre);                                                  \
    hself = ugv * hself + (1.0f - ugv) * cv;                                  \
    if (half == 0) hc[(LT) * 128 + o_r] = hself;                              \
  } while (0)

// ---------------------------------------------------------------------------
// Scan role. B0 (producer): hout=ring, releases flag1[c], guards ring slots
// via relaxed ack spins. B3 (consumer): acquire-spins f2a/f2b, hout=YS.
// ---------------------------------------------------------------------------
__device__ void scan_role(const float* __restrict__ A, const float* __restrict__ CX,
                          const float* __restrict__ Wgh, const float* __restrict__ Wch,
                          float* __restrict__ hout, int hout_is_ring,
                          float* __restrict__ hfinal,
                          int* relf, int* acka, int* ackb, int* wfa, int* wfb) {
  __shared__ float pg[256 * 5];
  __shared__ float pc[128 * 5];
  const int tid = threadIdx.x;
  const int w = tid >> 6;
  const int l = tid & 63;
  const int j = l & 31;
  const int half = l >> 5;
  const int o_r = 32 * w + j;
  const int o_u = o_r + 128;

  f2 wgt[16][4];
  f2 wct[16][2];
#pragma unroll
  for (int q = 0; q < 16; ++q) {
#pragma unroll
    for (int m = 0; m < 4; ++m) {
      wgt[q][m].x = Wgh[(32 * w + 2 * q) * 256 + l + 64 * m];
      wgt[q][m].y = Wgh[(32 * w + 2 * q + 1) * 256 + l + 64 * m];
    }
#pragma unroll
    for (int n = 0; n < 2; ++n) {
      wct[q][n].x = Wch[(32 * w + 2 * q) * 128 + l + 64 * n];
      wct[q][n].y = Wch[(32 * w + 2 * q + 1) * 128 + l + 64 * n];
    }
  }

  float hself = 0.0f;

  for (int c = 0; c < NCHUNK; ++c) {
    if (wfa) { spin_acq(&wfa[c]); spin_acq(&wfb[c]); }   // consumer gate (1 inv/chunk)
    if (relf && c >= RING) {                             // ring-slot free? (no fence)
      spin_rlx(&acka[c - RING]);
      spin_rlx(&ackb[c - RING]);
    }
    const float* Ac = A + (size_t)c * SCHUNK * 256;
    const float* Cc = CX + (size_t)c * SCHUNK * 128;
    float* hc = hout_is_ring ? hout + (size_t)(c & (RING - 1)) * SCHUNK * 128
                             : hout + (size_t)c * SCHUNK * 128;

    float arc[4], auc[4], cxc[4], arn[4], aun[4], cxn[4];
#pragma unroll
    for (int q = 0; q < 4; ++q) {
      arc[q] = Ac[q * 256 + o_r];
      auc[q] = Ac[q * 256 + o_u];
      cxc[q] = Cc[q * 128 + o_r];
    }
    for (int t0 = 0; t0 < SCHUNK; t0 += 4) {
      const int nb = (t0 + 4 < SCHUNK) ? t0 + 4 : 0;  // clamp inside chunk (safe)
#pragma unroll
      for (int q = 0; q < 4; ++q) {
        arn[q] = Ac[(nb + q) * 256 + o_r];
        aun[q] = Ac[(nb + q) * 256 + o_u];
        cxn[q] = Cc[(nb + q) * 128 + o_r];
      }
#pragma unroll
      for (int q = 0; q < 4; ++q) {
        GRU_STEP(t0 + q, arc[q], auc[q], cxc[q]);
      }
#pragma unroll
      for (int q = 0; q < 4; ++q) { arc[q] = arn[q]; auc[q] = aun[q]; cxc[q] = cxn[q]; }
    }
    if (relf) {
      __syncthreads();                 // drains all waves' ring stores (vmcnt 0)
      if (tid == 0) set_flag_rel(&relf[c]);
    }
  }
  if (half == 0) hfinal[o_r] = hself;
}

// ---------------------------------------------------------------------------
// Relay GEMV, gate half (N=256): per chunk, stage h1 chunk (64 KB) into LDS
// with coalesced float4 loads, ack the ring slot, then per step one coalesced
// ds_read_b64 + 128 compile-time readlane broadcasts + 64 pk-FMAs per lane.
// No dependent uniform global loads (the R4 killer).
// ---------------------------------------------------------------------------
__global__ void dummy_decl_anchor() {}  // (keeps section ordering tidy)

__device__ void gemv_gate_role(const float* __restrict__ ring,
                               const float* __restrict__ W,   // Wg2 x-rows [128][256]
                               const float* __restrict__ bias,
                               float* __restrict__ OUT,       // A2 [T][256]
                               int* inflag, int* ack, int* outflag) {
  __shared__ __align__(16) float hst[SCHUNK * 128];
  const int tid = threadIdx.x;
  const int l = tid & 63;
  const int col = tid;

  f2 wcol[64];
#pragma unroll
  for (int q = 0; q < 64; ++q) {
    wcol[q].x = W[(2 * q) * 256 + col];
    wcol[q].y = W[(2 * q + 1) * 256 + col];
  }
  const float bcol = bias[col];

  for (int c = 0; c < NCHUNK; ++c) {
    spin_acq(&inflag[c]);
    const f4* slot = (const f4*)(ring + (size_t)(c & (RING - 1)) * SCHUNK * 128);
    f4* hst4 = (f4*)hst;
#pragma unroll
    for (int q = 0; q < 16; ++q) hst4[tid + 256 * q] = slot[tid + 256 * q];
    __syncthreads();                       // staging complete (drains vm+lgkm)
    if (tid == 0) set_flag_rlx(&ack[c]);   // ring slot free (no data to order)

    float* outc = OUT + (size_t)c * SCHUNK * 256;
    for (int t = 0; t < SCHUNK; ++t) {
      f2 hreg = *(const f2*)&hst[t * 128 + 2 * l];
      f2 a0 = (f2)0.0f, a1 = (f2)0.0f, a2 = (f2)0.0f, a3 = (f2)0.0f;
#pragma unroll
      for (int q = 0; q < 16; ++q) {
        f2 h0, h1, h2, h3;
        h0.x = rdlane(hreg.x, 4 * q);     h0.y = rdlane(hreg.y, 4 * q);
        h1.x = rdlane(hreg.x, 4 * q + 1); h1.y = rdlane(hreg.y, 4 * q + 1);
        h2.x = rdlane(hreg.x, 4 * q + 2); h2.y = rdlane(hreg.y, 4 * q + 2);
        h3.x = rdlane(hreg.x, 4 * q + 3); h3.y = rdlane(hreg.y, 4 * q + 3);
        a0 = __builtin_elementwise_fma(h0, wcol[4 * q], a0);
        a1 = __builtin_elementwise_fma(h1, wcol[4 * q + 1], a1);
        a2 = __builtin_elementwise_fma(h2, wcol[4 * q + 2], a2);
        a3 = __builtin_elementwise_fma(h3, wcol[4 * q + 3], a3);
      }
      f2 s = (a0 + a1) + (a2 + a3);
      outc[t * 256 + col] = s.x + s.y + bcol;
    }
    __syncthreads();                       // drain A2 stores of this chunk
    if (tid == 0) set_flag_rel(&outflag[c]);
  }
}

// Relay GEMV, candidate half (N=128): 256 threads = (128 cols) x (2 step
// parities); each thread full-K over its parity's steps. No barriers in the
// step loop, ~15 us/chunk.
__device__ void gemv_cand_role(const float* __restrict__ ring,
                               const float* __restrict__ W,   // Wc2 x-rows [128][128]
                               const float* __restrict__ bias,
                               float* __restrict__ OUT,       // C2X [T][128]
                               int* inflag, int* ack, int* outflag) {
  __shared__ __align__(16) float hst[SCHUNK * 128];
  const int tid = threadIdx.x;
  const int l = tid & 63;
  const int col = tid & 127;
  const int par = tid >> 7;

  f2 wcol[64];
#pragma unroll
  for (int q = 0; q < 64; ++q) {
    wcol[q].x = W[(2 * q) * 128 + col];
    wcol[q].y = W[(2 * q + 1) * 128 + col];
  }
  const float bcol = bias[col];

  for (int c = 0; c < NCHUNK; ++c) {
    spin_acq(&inflag[c]);
    const f4* slot = (const f4*)(ring + (size_t)(c & (RING - 1)) * SCHUNK * 128);
    f4* hst4 = (f4*)hst;
#pragma unroll
    for (int q = 0; q < 16; ++q) hst4[tid + 256 * q] = slot[tid + 256 * q];
    __syncthreads();
    if (tid == 0) set_flag_rlx(&ack[c]);

    float* outc = OUT + (size_t)c * SCHUNK * 128;
    for (int s = 0; s < SCHUNK / 2; ++s) {
      const int t = 2 * s + par;
      f2 hreg = *(const f2*)&hst[t * 128 + 2 * l];
      f2 a0 = (f2)0.0f, a1 = (f2)0.0f, a2 = (f2)0.0f, a3 = (f2)0.0f;
#pragma unroll
      for (int q = 0; q < 16; ++q) {
        f2 h0, h1, h2, h3;
        h0.x = rdlane(hreg.x, 4 * q);     h0.y = rdlane(hreg.y, 4 * q);
        h1.x = rdlane(hreg.x, 4 * q + 1); h1.y = rdlane(hreg.y, 4 * q + 1);
        h2.x = rdlane(hreg.x, 4 * q + 2); h2.y = rdlane(hreg.y, 4 * q + 2);
        h3.x = rdlane(hreg.x, 4 * q + 3); h3.y = rdlane(hreg.y, 4 * q + 3);
        a0 = __builtin_elementwise_fma(h0, wcol[4 * q], a0);
        a1 = __builtin_elementwise_fma(h1, wcol[4 * q + 1], a1);
        a2 = __builtin_elementwise_fma(h2, wcol[4 * q + 2], a2);
        a3 = __builtin_elementwise_fma(h3, wcol[4 * q + 3], a3);
      }
      f2 sm = (a0 + a1) + (a2 + a3);
      outc[t * 128 + col] = sm.x + sm.y + bcol;
    }
    __syncthreads();
    if (tid == 0) set_flag_rel(&outflag[c]);
  }
}

// ---------------------------------------------------------------------------
// Pipeline kernel: 4 blocks = {scan1, gemv_gate, gemv_cand, scan2}.
// ---------------------------------------------------------------------------
__global__ __launch_bounds__(256, 1)
void pipeline(const float* __restrict__ A1, const float* __restrict__ C1X,
              const float* __restrict__ Wg1, const float* __restrict__ Wc1,
              const float* __restrict__ Wg2, const float* __restrict__ bg2,
              const float* __restrict__ Wc2, const float* __restrict__ bc2,
              float* ring, float* A2, float* C2X, float* YS,
              float* h1f, float* h2f, int* flags) {
  int* flag1 = flags;          // h1 chunk ready
  int* acka  = flags + 512;    // gate relay staged ring chunk
  int* ackb  = flags + 1024;   // cand relay staged ring chunk
  int* f2a   = flags + 1536;   // A2 chunk ready
  int* f2b   = flags + 2048;   // C2X chunk ready
  const int role = blockIdx.x;
  if (role == 0)
    scan_role(A1, C1X, Wg1 + 128 * 256, Wc1 + 128 * 128, ring, 1, h1f,
              flag1, acka, ackb, nullptr, nullptr);
  else if (role == 1)
    gemv_gate_role(ring, Wg2, bg2, A2, flag1, acka, f2a);
  else if (role == 2)
    gemv_cand_role(ring, Wc2, bc2, C2X, flag1, ackb, f2b);
  else
    scan_role(A2, C2X, Wg2 + 128 * 256, Wc2 + 128 * 128, YS, 0, h2f,
              nullptr, nullptr, nullptr, f2a, f2b);
}

// ---------------------------------------------------------------------------
// Final projections: logits = PI @ Wp + bp, value = V @ Wv + bv.
// ---------------------------------------------------------------------------
__global__ __launch_bounds__(256)
void proj_heads(const float* __restrict__ PI, const float* __restrict__ V,
                const float* __restrict__ Wp, const float* __restrict__ bp,
                const float* __restrict__ Wv, const float* __restrict__ bv,
                float* __restrict__ logits, float* __restrict__ value) {
  __shared__ float pi_t[128][101];
  __shared__ float v_t[128][101];
  __shared__ float wp_s[100][18];
  __shared__ float wv_s[100];
  __shared__ float bp_s[18];
  __shared__ float bv_s;
  const int tid = threadIdx.x;
  const int R0 = blockIdx.x * 128;

  for (int idx = tid; idx < 12800; idx += 256) {
    int r = idx / 100, c = idx - r * 100;
    pi_t[r][c] = PI[(size_t)R0 * 100 + idx];
    v_t[r][c] = V[(size_t)R0 * 100 + idx];
  }
  for (int idx = tid; idx < 1800; idx += 256) ((float*)wp_s)[idx] = Wp[idx];
  if (tid < 100) wv_s[tid] = Wv[tid];
  if (tid < 18) bp_s[tid] = bp[tid];
  if (tid == 0) bv_s = bv[0];
  __syncthreads();

  const int r = tid >> 1, h = tid & 1;
  float acc[9];
#pragma unroll
  for (int m = 0; m < 9; ++m) acc[m] = bp_s[h * 9 + m];
  float vacc = bv_s;
#pragma unroll 4
  for (int c = 0; c < 100; ++c) {
    float p = pi_t[r][c];
#pragma unroll
    for (int m = 0; m < 9; ++m) acc[m] = fmaf(p, wp_s[c][h * 9 + m], acc[m]);
    if (h) vacc = fmaf(v_t[r][c], wv_s[c], vacc);
  }
  size_t t = (size_t)R0 + r;
#pragma unroll
  for (int m = 0; m < 9; ++m) logits[t * 18 + h * 9 + m] = acc[m];
  if (h) value[t] = vacc;
}

// ---------------------------------------------------------------------------
extern "C" void kernel_launch(void* const* d_in, const int* in_sizes, int n_in,
                              void* d_out, int out_size, void* d_ws, size_t ws_size,
                              hipStream_t stream) {
  const float* obs = (const float*)d_in[0];
  const float* W1  = (const float*)d_in[1];
  const float* b1  = (const float*)d_in[2];
  const float* Wg1 = (const float*)d_in[3];
  const float* bg1 = (const float*)d_in[4];
  const float* Wc1 = (const float*)d_in[5];
  const float* bc1 = (const float*)d_in[6];
  const float* Wg2 = (const float*)d_in[7];
  const float* bg2 = (const float*)d_in[8];
  const float* Wc2 = (const float*)d_in[9];
  const float* bc2 = (const float*)d_in[10];
  const float* W2  = (const float*)d_in[11];
  const float* b2  = (const float*)d_in[12];
  const float* W3  = (const float*)d_in[13];
  const float* b3  = (const float*)d_in[14];
  const float* Wp  = (const float*)d_in[15];
  const float* bp  = (const float*)d_in[16];
  const float* Wv  = (const float*)d_in[17];
  const float* bv  = (const float*)d_in[18];

  float* out = (float*)d_out;
  float* ws  = (float*)d_ws;
  const int T = T_STEPS;

  float* A1   = ws + 0;           // also A2 (overwritten chunk-wise)
  float* C1X  = ws + 16777216;    // also C2X
  float* ring = ws + 25165824;    // h1 ring (8 x 128 x 128)
  int*   flags = (int*)(ws + 25296896);   // 2560 ints
  float* X    = ws + 33554432;    // phase-1 scratch (dead before YS)
  float* YS   = ws + 33554432;
  float* PIb  = ws + 0;           // phase-3 (A2 dead)
  float* Vb   = ws + 8388608;

  float* logits = out;
  float* value  = out + (size_t)T * 18;
  float* h1f    = out + (size_t)T * 18 + T;
  float* h2f    = h1f + 128;

  dim3 b256(256);
  // Reset handoff flags (graph-captured; runs every replay before pipeline).
  hipMemsetAsync(flags, 0, 2560 * sizeof(int), stream);
  // Parallel pre-pass: X = relu(obs@W1+b1); x-parts of GRU1 preactivations.
  gemm_k128<<<T / 32, b256, 0, stream>>>(obs, W1, b1, X, 128, 1);
  gemm_k128<<<T / 32, b256, 0, stream>>>(X, Wg1, bg1, A1, 256, 0);
  gemm_k128<<<T / 32, b256, 0, stream>>>(X, Wc1, bc1, C1X, 128, 0);
  // Pipelined phase: scan1 -> LDS-staged relay GEMVs -> scan2, concurrent.
  pipeline<<<4, b256, 0, stream>>>(A1, C1X, Wg1, Wc1, Wg2, bg2, Wc2, bc2,
                                   ring, A1 /*A2*/, C1X /*C2X*/, YS,
                                   h1f, h2f, flags);
  // Parallel heads.
  gemm_k128<<<T / 32, b256, 0, stream>>>(YS, W2, b2, PIb, 100, 1);
  gemm_k128<<<T / 32, b256, 0, stream>>>(YS, W3, b3, Vb, 100, 1);
  proj_heads<<<T / 128, b256, 0, stream>>>(PIb, Vb, Wp, bp, Wv, bv, logits, value);
}